// Round 20
// baseline (163.688 us; speedup 1.0000x reference)
//
#include <hip/hip_runtime.h>
#include <hip/hip_bf16.h>

#define N_ 16
#define D_ 2048
#define H_ 32
#define W_ 32
#define HW_ 1024
#define F_ 512

typedef unsigned short u16;
typedef unsigned int u32;
typedef __attribute__((ext_vector_type(8))) short bf16x8;
typedef __attribute__((ext_vector_type(4))) float f32x4;

__device__ __forceinline__ u16 f2bf(float f) {
  __hip_bfloat16 h = __float2bfloat16(f);
  union { __hip_bfloat16 h; u16 u; } c; c.h = h;
  return c.u;
}
__device__ __forceinline__ u32 f2bf2(float lo, float hi) {
  return (u32)f2bf(lo) | ((u32)f2bf(hi) << 16);
}
__device__ __forceinline__ float bflo(u32 u) { union { u32 u; float f; } c; c.u = u << 16; return c.f; }
__device__ __forceinline__ float bfhi(u32 u) { union { u32 u; float f; } c; c.u = u & 0xffff0000u; return c.f; }
__device__ __forceinline__ float bfu(u16 u) { union { u32 u; float f; } c; c.u = (u32)u << 16; return c.f; }

#define GLD_LDS16(gp, lp) __builtin_amdgcn_global_load_lds( \
    (const __attribute__((address_space(1))) void*)(gp), \
    (__attribute__((address_space(3))) void*)(lp), 16, 0, 0)

// ---- K0: zero sumsq (64 KB) ----
__global__ __launch_bounds__(256) void k_zero(float* __restrict__ p) {
  int i = blockIdx.x * 256 + threadIdx.x;
  ((float4*)p)[i] = (float4){0.f, 0.f, 0.f, 0.f};
}

// ---- K1: ONE pass over x: sumsq atomics + raw-x bf16 fragment-packed A ----
// grid (n=16, ht=8 [128 hw rows], dc=32 [64 d]); block 256.
// Phase 1: thread (dg d-pair, w4 w-quad) loads 4 h-rows x 2 d (8 float4),
// converts to bf16 d-pair u32s into sbox [128 hw][34]. Phase 2: thread pair
// (r,half) reads 32 bf16 of row r, accumulates sumsq partial (bf16-based,
// error ~0.01% after averaging 2048 terms) + packed writeout (proven layout).
__global__ __launch_bounds__(256) void k_sumsqpack(const float* __restrict__ x,
    float* __restrict__ sumsq, u16* __restrict__ packA) {
  const int n = blockIdx.x, ht = blockIdx.y, dc = blockIdx.z;
  const int h0 = ht * 4, d0 = dc * 64;
  const int t = threadIdx.x;
  const int w4 = t & 7, dg = t >> 3, wq = w4 * 4;

  __shared__ __align__(16) u32 sbox[128 * 34];

  const float* base0 = x + ((size_t)(n * D_ + d0 + dg * 2)) * HW_ + wq;
  const float* base1 = base0 + HW_;

  #pragma unroll
  for (int jj = 0; jj < 4; ++jj) {
    const int hp = h0 + jj;
    float4 a = *(const float4*)(base0 + hp * W_);
    float4 b = *(const float4*)(base1 + hp * W_);
    const int rb = jj * 32 + wq;
    sbox[(rb + 0) * 34 + dg] = f2bf2(a.x, b.x);
    sbox[(rb + 1) * 34 + dg] = f2bf2(a.y, b.y);
    sbox[(rb + 2) * 34 + dg] = f2bf2(a.z, b.z);
    sbox[(rb + 3) * 34 + dg] = f2bf2(a.w, b.w);
  }
  __syncthreads();

  {
    const int r = t >> 1, half = t & 1;
    const u32* srcp = sbox + r * 34 + half * 16;
    uint2 a[8];
    #pragma unroll
    for (int q = 0; q < 8; ++q) a[q] = *(const uint2*)(srcp + q * 2);

    // sumsq partial over this thread's 32 d's of row r
    float s = 0.f;
    #pragma unroll
    for (int q = 0; q < 8; ++q) {
      float v0 = bflo(a[q].x), v1 = bfhi(a[q].x);
      float v2 = bflo(a[q].y), v3 = bfhi(a[q].y);
      s += v0 * v0 + v1 * v1 + v2 * v2 + v3 * v3;
    }
    s += __shfl_xor(s, 1);
    if (half == 0) atomicAdd(&sumsq[n * HW_ + ht * 128 + r], s);

    // packed writeout (proven r8 layout)
    const int mt = n * 16 + ht * 2 + (r >> 6);
    const int mf = (r >> 4) & 3, r15 = r & 15;
    const int kt = dc * 2 + half;
    u16* dst = packA + ((size_t)(mt * 64 + kt) * 4 + mf) * 512 + r15 * 8;
    #pragma unroll
    for (int q = 0; q < 4; ++q) {        // q = hi
      uint4 b;
      b.x = a[2 * q].x; b.y = a[2 * q].y; b.z = a[2 * q + 1].x; b.w = a[2 * q + 1].y;
      *(uint4*)(dst + q * 128) = b;
    }
  }
}

// ---- K2: GeM pass: g[n][d] = sum_hw clip(xbf16*rn, 1e-6)^p from packA ----
// grid (n=16, kt=64), block 256 (4 waves = 4 mf). Plain stores (no zero/atomic).
__global__ __launch_bounds__(256) void k_gempass(const u16* __restrict__ packA,
    const float* __restrict__ sumsq, const float* __restrict__ pvec,
    float* __restrict__ gbuf) {
  const int n = blockIdx.x, kt = blockIdx.y;
  const int t = threadIdx.x, lane = t & 63, wv = t >> 6;
  const int r15 = lane & 15, hi = lane >> 4;
  const float p = pvec[0];
  const bool p3 = (p == 3.0f);

  __shared__ float rnl[1024];
  __shared__ float gtmp[4][32];

  for (int i = t; i < 1024; i += 256)
    rnl[i] = 1.0f / fmaxf(sqrtf(sumsq[n * HW_ + i]), 1e-12f);
  __syncthreads();

  float accv[8];
  #pragma unroll
  for (int e = 0; e < 8; ++e) accv[e] = 0.f;

  for (int mt = 0; mt < 16; ++mt) {
    const u16* src = packA + ((size_t)((n * 16 + mt) * 64 + kt) * 4 + wv) * 512 + lane * 8;
    bf16x8 v = *(const bf16x8*)src;
    float rnv = rnl[mt * 64 + wv * 16 + r15];
    #pragma unroll
    for (int e = 0; e < 8; ++e) {
      float c = fmaxf(bfu((u16)v[e]) * rnv, 1e-6f);
      accv[e] += p3 ? c * c * c : __powf(c, p);
    }
  }
  #pragma unroll
  for (int e = 0; e < 8; ++e) {
    accv[e] += __shfl_xor(accv[e], 1, 16);
    accv[e] += __shfl_xor(accv[e], 2, 16);
    accv[e] += __shfl_xor(accv[e], 4, 16);
    accv[e] += __shfl_xor(accv[e], 8, 16);
  }
  if (r15 == 0) {
    #pragma unroll
    for (int e = 0; e < 8; ++e) gtmp[wv][hi * 8 + e] = accv[e];
  }
  __syncthreads();
  if (t < 32) {
    float g = gtmp[0][t] + gtmp[1][t] + gtmp[2][t] + gtmp[3][t];
    gbuf[n * D_ + kt * 32 + t] = g;
  }
}

// ---- K3: proj_w fp32 -> bf16, fragment-packed: packB[wq][kt][nf][lane][8] ----
__global__ __launch_bounds__(256) void k_wconv(const float* __restrict__ w, u16* __restrict__ packB) {
  const int i = blockIdx.x * 256 + threadIdx.x;   // 0..131071
  const int lane = i & 63, nf = (i >> 6) & 3, kt = (i >> 8) & 63, wq = i >> 14;
  const int r15 = lane & 15, hi = lane >> 4;
  const int f = wq * 64 + nf * 16 + r15;
  const int k = kt * 32 + hi * 8;
  const float* src = w + (size_t)f * D_ + k;
  float4 v0 = *(const float4*)(src);
  float4 v1 = *(const float4*)(src + 4);
  u32 r[4] = { f2bf2(v0.x, v0.y), f2bf2(v0.z, v0.w),
               f2bf2(v1.x, v1.y), f2bf2(v1.z, v1.w) };
  *(uint4*)(packB + (size_t)i * 8) = *(const uint4*)r;
}

// ---- K4: GEMM [64 hw] x [512 f] x [K 2048] (r13 pipeline) ----
// Epilogue: scale row by rn[hw] (x-normalization, commuted past the GEMM);
// NO bias, NO f-l2norm (both move to k_boxf). Writes y = rn*(x@W^T) fp32.
__global__ __launch_bounds__(512) void k_gemm(const u16* __restrict__ packA,
    const u16* __restrict__ packB, const float* __restrict__ sumsq,
    float* __restrict__ y) {
  const int n  = blockIdx.x >> 4;
  const int mtl = blockIdx.x & 15;
  const int mt = blockIdx.x;
  const int hw0 = mtl * 64;
  const int t = threadIdx.x;
  const int lane = t & 63, wv = t >> 6;
  const int r15 = lane & 15, hi = lane >> 4;

  __shared__ __align__(16) float smem_f[128 * 68];   // A bufs alias first 16 KB
  __shared__ float s_rn[64];

  f32x4 acc[4][4];
  #pragma unroll
  for (int a = 0; a < 4; ++a)
    #pragma unroll
    for (int b = 0; b < 4; ++b) acc[a][b] = (f32x4){0.f, 0.f, 0.f, 0.f};

  const u16* asrc = packA + ((size_t)(mt * 64) * 4 + (wv & 3)) * 512 + lane * 8;
  const u16* bbase = packB + (size_t)wv * 131072 + lane * 8;

#define STAGE_A(KT) GLD_LDS16(asrc + (size_t)(KT) * 2048, \
    (char*)smem_f + ((KT) & 3) * 4096 + (wv & 3) * 1024)

  STAGE_A(0);
  STAGE_A(1);
  bf16x8 bc[4], bn[4];
  #pragma unroll
  for (int nf = 0; nf < 4; ++nf) bc[nf] = *(const bf16x8*)(bbase + nf * 512);

  for (int kt = 0; kt < 64; ++kt) {
    if (kt + 2 < 64) STAGE_A(kt + 2);
    if (kt + 1 < 64) {
      #pragma unroll
      for (int nf = 0; nf < 4; ++nf)
        bn[nf] = *(const bf16x8*)(bbase + ((kt + 1) * 4 + nf) * 512);
    }
    __builtin_amdgcn_sched_barrier(0);
    if (kt < 62) {
      asm volatile("s_waitcnt vmcnt(5)" ::: "memory");
    } else if (kt == 62) {
      asm volatile("s_waitcnt vmcnt(4)" ::: "memory");
    } else {
      asm volatile("s_waitcnt vmcnt(0)" ::: "memory");
    }
    __builtin_amdgcn_sched_barrier(0);
    __builtin_amdgcn_s_barrier();
    __builtin_amdgcn_sched_barrier(0);

    const u16* sA = (const u16*)((const char*)smem_f + (kt & 3) * 4096);
    bf16x8 af[4];
    #pragma unroll
    for (int mf = 0; mf < 4; ++mf)
      af[mf] = *(const bf16x8*)(sA + mf * 512 + lane * 8);
    #pragma unroll
    for (int mf = 0; mf < 4; ++mf)
      #pragma unroll
      for (int nf = 0; nf < 4; ++nf)
        acc[mf][nf] = __builtin_amdgcn_mfma_f32_16x16x32_bf16(af[mf], bc[nf], acc[mf][nf], 0, 0, 0);
    #pragma unroll
    for (int nf = 0; nf < 4; ++nf) bc[nf] = bn[nf];
  }
#undef STAGE_A

  // epilogue: rn[hw] row-scale + transposed store of y
  __syncthreads();                        // all MFMA LDS reads done
  if (t < 64) s_rn[t] = 1.0f / fmaxf(sqrtf(sumsq[n * HW_ + hw0 + t]), 1e-12f);
  __syncthreads();

  float* ct = smem_f;   // [128 f-rows][68] fp32
  for (int nf = 0; nf < 4; ++nf) {
    const int fi = wv * 16 + r15;
    #pragma unroll
    for (int mf = 0; mf < 4; ++mf)
      #pragma unroll
      for (int j = 0; j < 4; ++j) {
        int m = mf * 16 + hi * 4 + j;
        ct[fi * 68 + m] = acc[mf][nf][j] * s_rn[m];
      }
    __syncthreads();
    {
      int fr = t >> 2, mq = t & 3;
      int f = (fr >> 4) * 64 + nf * 16 + (fr & 15);
      float* dst = y + ((size_t)(n * F_ + f)) * HW_ + hw0 + mq * 16;
      const float* srcp = ct + fr * 68 + mq * 16;
      float4 a0 = *(const float4*)(srcp);
      float4 a1 = *(const float4*)(srcp + 4);
      float4 a2 = *(const float4*)(srcp + 8);
      float4 a3 = *(const float4*)(srcp + 12);
      *(float4*)(dst) = a0; *(float4*)(dst + 4) = a1;
      *(float4*)(dst + 8) = a2; *(float4*)(dst + 12) = a3;
    }
    __syncthreads();
  }
}

// ---- K4b: box over y (3x3 truncated, zero-padded) + bias + l2norm over f ----
// grid (n=16, hb=16 [64 hw]), block 512. lane = local hw (h1=lane>>5, w=lane&31);
// wave wv handles f = wv*64 + it. Vertical 3-tap in-thread, horizontal via shfl.
__global__ __launch_bounds__(512) void k_boxf(const float* __restrict__ y,
    const float* __restrict__ bias, float* __restrict__ pdt,
    float* __restrict__ outL) {
  const int n = blockIdx.x, hb = blockIdx.y;
  const int t = threadIdx.x, lane = t & 63, wv = t >> 6;
  const int h1 = lane >> 5, w = lane & 31;
  const int h_out = hb * 2 + h1;

  __shared__ float wsq[8][64];
  __shared__ float srn[64];

  const size_t ybase = (size_t)n * F_ * HW_;
  float* pbase = pdt + ((size_t)(n * 16 + hb)) * F_ * 64;

  float accsq = 0.f;
  const bool up_ok = (h_out - 1 >= 0), dn_ok = (h_out + 1 < H_);
  for (int it = 0; it < 64; ++it) {
    const int f = wv * 64 + it;
    const float* yf = y + ybase + (size_t)f * HW_;
    float l0 = up_ok ? yf[(h_out - 1) * W_ + w] : 0.f;
    float l1 = yf[h_out * W_ + w];
    float l2 = dn_ok ? yf[(h_out + 1) * W_ + w] : 0.f;
    float vs = l0 + l1 + l2;
    float lf = __shfl_up(vs, 1, 32);
    float rf = __shfl_down(vs, 1, 32);
    if (w == 0) lf = 0.f;
    if (w == 31) rf = 0.f;
    float pd = lf + vs + rf + bias[f];
    accsq += pd * pd;
    pbase[(size_t)f * 64 + lane] = pd;
  }
  wsq[wv][lane] = accsq;
  __syncthreads();
  if (t < 64) {
    float s = 0.f;
    #pragma unroll
    for (int w8 = 0; w8 < 8; ++w8) s += wsq[w8][t];
    srn[t] = 1.0f / fmaxf(sqrtf(s), 1e-12f);
  }
  __syncthreads();
  for (int it = 0; it < 64; ++it) {
    const int f = wv * 64 + it;
    float pv = pbase[(size_t)f * 64 + lane];
    outL[ybase + (size_t)f * HW_ + hb * 64 + lane] = pv * srn[lane];
  }
}

// ---- K5: GeM finalize: gg = (gbuf/1024)^(1/p) ----
__global__ __launch_bounds__(256) void k_gem_fin(const float* __restrict__ gbuf,
    const float* __restrict__ pvec, float* __restrict__ gg) {
  int i = blockIdx.x * 256 + threadIdx.x;
  float p = pvec[0];
  float m = gbuf[i] * (1.0f / 1024.0f);
  gg[i] = (p == 3.0f) ? cbrtf(m) : powf(m, 1.0f / p);
}

// ---- K6: gproj[n][f] = dot(gg[n], W[f]) + b[f] ----
__global__ __launch_bounds__(256) void k_gproj(const float* __restrict__ w,
    const float* __restrict__ bias, const float* __restrict__ gg,
    float* __restrict__ gproj) {
  const int f = blockIdx.x;
  const int t = threadIdx.x;
  float wreg[8];
  #pragma unroll
  for (int j = 0; j < 8; ++j) wreg[j] = w[(size_t)f * D_ + t + j * 256];
  __shared__ float red[4];
  const int lane = t & 63, wv = t >> 6;
  for (int n = 0; n < N_; ++n) {
    float s = 0.f;
    #pragma unroll
    for (int j = 0; j < 8; ++j) s += wreg[j] * gg[n * D_ + t + j * 256];
    #pragma unroll
    for (int off = 32; off >= 1; off >>= 1) s += __shfl_down(s, off);
    if (lane == 0) red[wv] = s;
    __syncthreads();
    if (t == 0) gproj[n * F_ + f] = red[0] + red[1] + red[2] + red[3] + bias[f];
    __syncthreads();
  }
}

// ---- K7: l2norm g rows -> d_out[0:8192] ----
__global__ __launch_bounds__(512) void k_gnorm(const float* __restrict__ gproj, float* __restrict__ outg) {
  const int n = blockIdx.x;
  const int t = threadIdx.x;
  float v = gproj[n * F_ + t];
  float s = v * v;
  const int lane = t & 63, wv = t >> 6;
  #pragma unroll
  for (int off = 32; off >= 1; off >>= 1) s += __shfl_down(s, off);
  __shared__ float red[8];
  __shared__ float rtot;
  if (lane == 0) red[wv] = s;
  __syncthreads();
  if (t == 0) {
    float a = 0.f;
    #pragma unroll
    for (int i = 0; i < 8; ++i) a += red[i];
    rtot = 1.0f / fmaxf(sqrtf(a), 1e-12f);
  }
  __syncthreads();
  outg[n * F_ + t] = v * rtot;
}

extern "C" void kernel_launch(void* const* d_in, const int* in_sizes, int n_in,
                              void* d_out, int out_size, void* d_ws, size_t ws_size,
                              hipStream_t stream) {
  const float* x  = (const float*)d_in[0];
  const float* pw = (const float*)d_in[1];
  const float* pb = (const float*)d_in[2];
  const float* pv = (const float*)d_in[3];
  float* out = (float*)d_out;

  char* ws = (char*)d_ws;
  float* sumsq = (float*)ws;                                   // 64 KB
  float* gbuf  = (float*)(ws + 65536);                         // 128 KB (plain stores)
  float* gg    = (float*)(ws + 65536 + 131072);                // 128 KB
  float* gproj = (float*)(ws + 65536 + 2 * 131072);            // 32 KB
  u16*   packB = (u16*)(ws + 65536 + 2 * 131072 + 32768);      // 2 MiB
  u16*   packA = (u16*)(ws + 4u * 1024u * 1024u);              // 64 MiB
  float* ybuf  = (float*)(ws + 68u * 1024u * 1024u);           // 32 MiB
  float* pdt   = (float*)(ws + 100u * 1024u * 1024u);          // 32 MiB

  k_zero<<<dim3(16), dim3(256), 0, stream>>>(sumsq);
  k_wconv<<<dim3(512), dim3(256), 0, stream>>>(pw, packB);
  k_sumsqpack<<<dim3(16, 8, 32), dim3(256), 0, stream>>>(x, sumsq, packA);
  k_gempass<<<dim3(16, 64), dim3(256), 0, stream>>>(packA, sumsq, pv, gbuf);
  k_gem_fin<<<dim3(128), dim3(256), 0, stream>>>(gbuf, pv, gg);
  k_gproj<<<dim3(512), dim3(256), 0, stream>>>(pw, pb, gg, gproj);
  k_gnorm<<<dim3(16), dim3(512), 0, stream>>>(gproj, out);
  k_gemm<<<dim3(256), dim3(512), 0, stream>>>(packA, packB, sumsq, ybuf);
  k_boxf<<<dim3(16, 16), dim3(512), 0, stream>>>(ybuf, pb, pdt, out + N_ * F_);
}

// Round 21
// 139.585 us; speedup vs baseline: 1.1727x; 1.1727x over previous
//
#include <hip/hip_runtime.h>
#include <hip/hip_bf16.h>

#define N_ 16
#define D_ 2048
#define H_ 32
#define W_ 32
#define HW_ 1024
#define F_ 512

typedef unsigned short u16;
typedef unsigned int u32;
typedef __attribute__((ext_vector_type(8))) short bf16x8;
typedef __attribute__((ext_vector_type(4))) float f32x4;

__device__ __forceinline__ u16 f2bf(float f) {
  union { float fv; u32 u; } c; c.fv = f;
  u32 u = c.u;
  u32 r = (u + 0x7fffu + ((u >> 16) & 1u)) >> 16;   // RNE
  return (u16)r;
}

#define GLD_LDS16(gp, lp) __builtin_amdgcn_global_load_lds( \
    (const __attribute__((address_space(1))) void*)(gp), \
    (__attribute__((address_space(3))) void*)(lp), 16, 0, 0)

// ---- K0: zero sumsq+gbuf (192 KB contiguous) ----
__global__ __launch_bounds__(256) void k_zero(float* __restrict__ p) {
  int i = blockIdx.x * 256 + threadIdx.x;
  ((float4*)p)[i] = (float4){0.f, 0.f, 0.f, 0.f};
}

// ---- K1: sum of squares over channel dim -> sumsq[n][hw] (atomic partials) ----
__global__ __launch_bounds__(256) void k_sumsq(const float* __restrict__ x, float* __restrict__ sumsq) {
  const int n = blockIdx.x;        // 16
  const int dc = blockIdx.y;       // 32 chunks x 64 d
  const int t = threadIdx.x;
  const float* xp = x + ((size_t)n * D_ + (size_t)dc * 64) * HW_;
  float s0 = 0.f, s1 = 0.f, s2 = 0.f, s3 = 0.f;
  for (int d = 0; d < 64; ++d) {
    const float* row = xp + (size_t)d * HW_;
    float v0 = row[t], v1 = row[t + 256], v2 = row[t + 512], v3 = row[t + 768];
    s0 += v0 * v0; s1 += v1 * v1; s2 += v2 * v2; s3 += v3 * v3;
  }
  atomicAdd(&sumsq[n * HW_ + t      ], s0);
  atomicAdd(&sumsq[n * HW_ + t + 256], s1);
  atomicAdd(&sumsq[n * HW_ + t + 512], s2);
  atomicAdd(&sumsq[n * HW_ + t + 768], s3);
}

// ---- K2: float4-vectorized separable 3x3 box + GeM partials (r13 form) ----
__global__ __launch_bounds__(256) void k_box2(const float* __restrict__ x,
    const float* __restrict__ sumsq, const float* __restrict__ pvec,
    float* __restrict__ gbuf, u16* __restrict__ packA) {
  const int n = blockIdx.x, ht = blockIdx.y, dc = blockIdx.z;
  const int h0 = ht * 4, d0 = dc * 64;
  const int t = threadIdx.x;
  const int w4 = t & 7, dg = t >> 3;
  const int wq = w4 * 4;
  const float p = pvec[0];
  const bool p3 = (p == 3.0f);

  __shared__ __align__(16) u16 sbox[128 * 68];   // [hw 128][d 64 pad->68]
  __shared__ __align__(16) float rnl[6][32];

  if (t < 192) {
    int jj = t >> 5, w = t & 31;
    int hp = h0 - 1 + jj;
    float r = 0.f;
    if (hp >= 0 && hp < H_) r = 1.0f / fmaxf(sqrtf(sumsq[n * HW_ + hp * W_ + w]), 1e-12f);
    rnl[jj][w] = r;
  }
  __syncthreads();

  float s0 = 0.f, s1 = 0.f;
  #pragma unroll
  for (int dj = 0; dj < 2; ++dj) {
    const int d = d0 + dg * 2 + dj;
    const float* base = x + ((size_t)(n * D_ + d)) * HW_ + wq;
    float4 v[6];
    #pragma unroll
    for (int jj = 0; jj < 6; ++jj) {
      int hp = h0 - 1 + jj;
      if (hp >= 0 && hp < H_) {
        float4 xv = *(const float4*)(base + hp * W_);
        float4 rr = *(const float4*)(&rnl[jj][wq]);
        v[jj].x = xv.x * rr.x; v[jj].y = xv.y * rr.y;
        v[jj].z = xv.z * rr.z; v[jj].w = xv.w * rr.w;
      } else {
        v[jj] = (float4){0.f, 0.f, 0.f, 0.f};
      }
    }
    float g = 0.f;
    #pragma unroll
    for (int jj = 1; jj <= 4; ++jj) {
      float cx = fmaxf(v[jj].x, 1e-6f), cy = fmaxf(v[jj].y, 1e-6f);
      float cz = fmaxf(v[jj].z, 1e-6f), cw = fmaxf(v[jj].w, 1e-6f);
      if (p3) g += cx * cx * cx + cy * cy * cy + cz * cz * cz + cw * cw * cw;
      else    g += __powf(cx, p) + __powf(cy, p) + __powf(cz, p) + __powf(cw, p);
    }
    if (dj == 0) s0 = g; else s1 = g;
    #pragma unroll
    for (int jj = 0; jj < 6; ++jj) {
      float lf = __shfl_up(v[jj].w, 1, 8);
      float rf = __shfl_down(v[jj].x, 1, 8);
      if (w4 == 0) lf = 0.f;
      if (w4 == 7) rf = 0.f;
      float4 h;
      h.x = lf + v[jj].x + v[jj].y;
      h.y = v[jj].x + v[jj].y + v[jj].z;
      h.z = v[jj].y + v[jj].z + v[jj].w;
      h.w = v[jj].z + v[jj].w + rf;
      v[jj] = h;
    }
    #pragma unroll
    for (int k = 0; k < 4; ++k) {
      float4 b;
      b.x = v[k].x + v[k + 1].x + v[k + 2].x;
      b.y = v[k].y + v[k + 1].y + v[k + 2].y;
      b.z = v[k].z + v[k + 1].z + v[k + 2].z;
      b.w = v[k].w + v[k + 1].w + v[k + 2].w;
      const int rb = k * 32 + wq;
      sbox[(rb + 0) * 68 + dg * 2 + dj] = f2bf(b.x);
      sbox[(rb + 1) * 68 + dg * 2 + dj] = f2bf(b.y);
      sbox[(rb + 2) * 68 + dg * 2 + dj] = f2bf(b.z);
      sbox[(rb + 3) * 68 + dg * 2 + dj] = f2bf(b.w);
    }
  }
  __syncthreads();

  {
    const int r = t >> 1, half = t & 1;
    const u16* srcp = sbox + r * 68 + half * 32;
    uint2 a[8];
    #pragma unroll
    for (int q = 0; q < 8; ++q) a[q] = *(const uint2*)(srcp + q * 4);
    const int mt = n * 16 + ht * 2 + (r >> 6);
    const int mf = (r >> 4) & 3, r15 = r & 15;
    const int kt = dc * 2 + half;
    u16* dst = packA + ((size_t)(mt * 64 + kt) * 4 + mf) * 512 + r15 * 8;
    #pragma unroll
    for (int q = 0; q < 4; ++q) {        // q = hi
      uint4 b;
      b.x = a[2 * q].x; b.y = a[2 * q].y; b.z = a[2 * q + 1].x; b.w = a[2 * q + 1].y;
      *(uint4*)(dst + q * 128) = b;
    }
  }

  {
    float v0 = s0, v1 = s1;
    v0 += __shfl_xor(v0, 1, 8); v1 += __shfl_xor(v1, 1, 8);
    v0 += __shfl_xor(v0, 2, 8); v1 += __shfl_xor(v1, 2, 8);
    v0 += __shfl_xor(v0, 4, 8); v1 += __shfl_xor(v1, 4, 8);
    if (w4 == 0) {
      atomicAdd(&gbuf[n * D_ + d0 + dg * 2    ], v0);
      atomicAdd(&gbuf[n * D_ + d0 + dg * 2 + 1], v1);
    }
  }
}

// ---- K3: proj_w fp32 -> bf16, fragment-packed: packB[wq][kt][nf][lane][8] ----
__global__ __launch_bounds__(256) void k_wconv(const float* __restrict__ w, u16* __restrict__ packB) {
  const int i = blockIdx.x * 256 + threadIdx.x;   // 0..131071
  const int lane = i & 63, nf = (i >> 6) & 3, kt = (i >> 8) & 63, wq = i >> 14;  // wq 0..7
  const int r15 = lane & 15, hi = lane >> 4;
  const int f = wq * 64 + nf * 16 + r15;
  const int k = kt * 32 + hi * 8;
  const float* src = w + (size_t)f * D_ + k;
  float4 v0 = *(const float4*)(src);
  float4 v1 = *(const float4*)(src + 4);
  u16 r[8] = { f2bf(v0.x), f2bf(v0.y), f2bf(v0.z), f2bf(v0.w),
               f2bf(v1.x), f2bf(v1.y), f2bf(v1.z), f2bf(v1.w) };
  *(uint4*)(packB + (size_t)i * 8) = *(const uint4*)r;
}

// ---- K4: GEMM [64 hw] x [512 f] x [K 2048] (r8/r13 form, best measured) ----
// 4-buf A via global_load_lds, B->reg lead-1, counted vmcnt 5/4/0, one
// s_barrier per step; all loads contiguous 1KB dwordx4; ds_reads lane-linear.
__global__ __launch_bounds__(512) void k_gemm(const u16* __restrict__ packA,
    const u16* __restrict__ packB, const float* __restrict__ bias,
    float* __restrict__ outL) {
  const int n  = blockIdx.x >> 4;
  const int mtl = blockIdx.x & 15;
  const int mt = blockIdx.x;            // global 64-row tile index
  const int hw0 = mtl * 64;
  const int t = threadIdx.x;
  const int lane = t & 63, wv = t >> 6;
  const int r15 = lane & 15, hi = lane >> 4;

  __shared__ __align__(16) float smem_f[128 * 68];   // 34.8 KB; A bufs alias first 16 KB
  __shared__ float s_sq[8][64];
  __shared__ float s_rn[64];

  f32x4 acc[4][4];
  #pragma unroll
  for (int a = 0; a < 4; ++a)
    #pragma unroll
    for (int b = 0; b < 4; ++b) acc[a][b] = (f32x4){0.f, 0.f, 0.f, 0.f};

  const u16* asrc = packA + ((size_t)(mt * 64) * 4 + (wv & 3)) * 512 + lane * 8;
  const u16* bbase = packB + (size_t)wv * 131072 + lane * 8;

#define STAGE_A(KT) GLD_LDS16(asrc + (size_t)(KT) * 2048, \
    (char*)smem_f + ((KT) & 3) * 4096 + (wv & 3) * 1024)

  STAGE_A(0);
  STAGE_A(1);
  bf16x8 bc[4], bn[4];
  #pragma unroll
  for (int nf = 0; nf < 4; ++nf) bc[nf] = *(const bf16x8*)(bbase + nf * 512);

  for (int kt = 0; kt < 64; ++kt) {
    if (kt + 2 < 64) STAGE_A(kt + 2);
    if (kt + 1 < 64) {
      #pragma unroll
      for (int nf = 0; nf < 4; ++nf)
        bn[nf] = *(const bf16x8*)(bbase + ((kt + 1) * 4 + nf) * 512);
    }
    __builtin_amdgcn_sched_barrier(0);
    if (kt < 62) {
      asm volatile("s_waitcnt vmcnt(5)" ::: "memory");   // A(kt)+B(kt) retired
    } else if (kt == 62) {
      asm volatile("s_waitcnt vmcnt(4)" ::: "memory");
    } else {
      asm volatile("s_waitcnt vmcnt(0)" ::: "memory");
    }
    __builtin_amdgcn_sched_barrier(0);
    __builtin_amdgcn_s_barrier();                         // A tile kt visible
    __builtin_amdgcn_sched_barrier(0);

    const u16* sA = (const u16*)((const char*)smem_f + (kt & 3) * 4096);
    bf16x8 af[4];
    #pragma unroll
    for (int mf = 0; mf < 4; ++mf)
      af[mf] = *(const bf16x8*)(sA + mf * 512 + lane * 8);
    #pragma unroll
    for (int mf = 0; mf < 4; ++mf)
      #pragma unroll
      for (int nf = 0; nf < 4; ++nf)
        acc[mf][nf] = __builtin_amdgcn_mfma_f32_16x16x32_bf16(af[mf], bc[nf], acc[mf][nf], 0, 0, 0);
    #pragma unroll
    for (int nf = 0; nf < 4; ++nf) bc[nf] = bn[nf];
  }
#undef STAGE_A

  // epilogue: bias, per-row (hw) l2 norm over all 512 f, transposed store
  float badd[4];
  #pragma unroll
  for (int nf = 0; nf < 4; ++nf) badd[nf] = bias[wv * 64 + nf * 16 + r15];
  #pragma unroll
  for (int mf = 0; mf < 4; ++mf)
    #pragma unroll
    for (int nf = 0; nf < 4; ++nf)
      #pragma unroll
      for (int j = 0; j < 4; ++j) acc[mf][nf][j] += badd[nf];

  #pragma unroll
  for (int mf = 0; mf < 4; ++mf)
    #pragma unroll
    for (int j = 0; j < 4; ++j) {
      float s = 0.f;
      #pragma unroll
      for (int nf = 0; nf < 4; ++nf) { float v = acc[mf][nf][j]; s += v * v; }
      s += __shfl_xor(s, 1); s += __shfl_xor(s, 2); s += __shfl_xor(s, 4); s += __shfl_xor(s, 8);
      if ((lane & 15) == 0) s_sq[wv][mf * 16 + hi * 4 + j] = s;
    }
  __syncthreads();
  if (t < 64) {
    float s = 0.f;
    #pragma unroll
    for (int w8 = 0; w8 < 8; ++w8) s += s_sq[w8][t];
    s_rn[t] = 1.0f / fmaxf(sqrtf(s), 1e-12f);
  }
  __syncthreads();

  float* ct = smem_f;   // [128 f-rows][68] fp32
  for (int nf = 0; nf < 4; ++nf) {
    const int fi = wv * 16 + r15;
    #pragma unroll
    for (int mf = 0; mf < 4; ++mf)
      #pragma unroll
      for (int j = 0; j < 4; ++j) {
        int m = mf * 16 + hi * 4 + j;
        ct[fi * 68 + m] = acc[mf][nf][j] * s_rn[m];
      }
    __syncthreads();
    {
      int fr = t >> 2, mq = t & 3;
      int f = (fr >> 4) * 64 + nf * 16 + (fr & 15);
      float* dst = outL + ((size_t)(n * F_ + f)) * HW_ + hw0 + mq * 16;
      const float* srcp = ct + fr * 68 + mq * 16;
      float4 a0 = *(const float4*)(srcp);
      float4 a1 = *(const float4*)(srcp + 4);
      float4 a2 = *(const float4*)(srcp + 8);
      float4 a3 = *(const float4*)(srcp + 12);
      *(float4*)(dst) = a0; *(float4*)(dst + 4) = a1;
      *(float4*)(dst + 8) = a2; *(float4*)(dst + 12) = a3;
    }
    __syncthreads();
  }
}

// ---- K5: GeM finalize: gg = (gbuf/1024)^(1/p) ----
__global__ __launch_bounds__(256) void k_gem_fin(const float* __restrict__ gbuf,
    const float* __restrict__ pvec, float* __restrict__ gg) {
  int i = blockIdx.x * 256 + threadIdx.x;
  float p = pvec[0];
  float m = gbuf[i] * (1.0f / 1024.0f);
  gg[i] = (p == 3.0f) ? cbrtf(m) : powf(m, 1.0f / p);
}

// ---- K6: gproj[n][f] = dot(gg[n], W[f]) + b[f] ----
__global__ __launch_bounds__(256) void k_gproj(const float* __restrict__ w,
    const float* __restrict__ bias, const float* __restrict__ gg,
    float* __restrict__ gproj) {
  const int f = blockIdx.x;
  const int t = threadIdx.x;
  float wreg[8];
  #pragma unroll
  for (int j = 0; j < 8; ++j) wreg[j] = w[(size_t)f * D_ + t + j * 256];
  __shared__ float red[4];
  const int lane = t & 63, wv = t >> 6;
  for (int n = 0; n < N_; ++n) {
    float s = 0.f;
    #pragma unroll
    for (int j = 0; j < 8; ++j) s += wreg[j] * gg[n * D_ + t + j * 256];
    #pragma unroll
    for (int off = 32; off >= 1; off >>= 1) s += __shfl_down(s, off);
    if (lane == 0) red[wv] = s;
    __syncthreads();
    if (t == 0) gproj[n * F_ + f] = red[0] + red[1] + red[2] + red[3] + bias[f];
    __syncthreads();
  }
}

// ---- K7: l2norm g rows -> d_out[0:8192] ----
__global__ __launch_bounds__(512) void k_gnorm(const float* __restrict__ gproj, float* __restrict__ outg) {
  const int n = blockIdx.x;
  const int t = threadIdx.x;
  float v = gproj[n * F_ + t];
  float s = v * v;
  const int lane = t & 63, wv = t >> 6;
  #pragma unroll
  for (int off = 32; off >= 1; off >>= 1) s += __shfl_down(s, off);
  __shared__ float red[8];
  __shared__ float rtot;
  if (lane == 0) red[wv] = s;
  __syncthreads();
  if (t == 0) {
    float a = 0.f;
    #pragma unroll
    for (int i = 0; i < 8; ++i) a += red[i];
    rtot = 1.0f / fmaxf(sqrtf(a), 1e-12f);
  }
  __syncthreads();
  outg[n * F_ + t] = v * rtot;
}

extern "C" void kernel_launch(void* const* d_in, const int* in_sizes, int n_in,
                              void* d_out, int out_size, void* d_ws, size_t ws_size,
                              hipStream_t stream) {
  const float* x  = (const float*)d_in[0];
  const float* pw = (const float*)d_in[1];
  const float* pb = (const float*)d_in[2];
  const float* pv = (const float*)d_in[3];
  float* out = (float*)d_out;

  char* ws = (char*)d_ws;
  float* sumsq = (float*)ws;                                   // 64 KB
  float* gbuf  = (float*)(ws + 65536);                         // 128 KB
  float* gg    = (float*)(ws + 65536 + 131072);                // 128 KB
  float* gproj = (float*)(ws + 65536 + 2 * 131072);            // 32 KB
  u16*   packB = (u16*)(ws + 65536 + 2 * 131072 + 32768);      // 2 MiB
  u16*   packA = (u16*)(ws + 4u * 1024u * 1024u);              // 64 MiB

  k_zero<<<dim3(48), dim3(256), 0, stream>>>(sumsq);           // sumsq + gbuf
  k_sumsq<<<dim3(16, 32), dim3(256), 0, stream>>>(x, sumsq);
  k_wconv<<<dim3(512), dim3(256), 0, stream>>>(pw, packB);
  k_box2<<<dim3(16, 8, 32), dim3(256), 0, stream>>>(x, sumsq, pv, gbuf, packA);
  k_gem_fin<<<dim3(128), dim3(256), 0, stream>>>(gbuf, pv, gg);
  k_gproj<<<dim3(512), dim3(256), 0, stream>>>(pw, pb, gg, gproj);
  k_gnorm<<<dim3(16), dim3(512), 0, stream>>>(gproj, out);
  k_gemm<<<dim3(256), dim3(512), 0, stream>>>(packA, packB, pb, out + N_ * F_);
}